// Round 5
// baseline (13032.738 us; speedup 1.0000x reference)
//
#include <hip/hip_runtime.h>
#include <math.h>

#define L 256
#define P 1024
#define P1 1025
#define TWOL 512
#define NBLK 32
#define TPB 512

typedef unsigned long long u64;

// ws offsets (float units)
#define OFF_VH   0                          // [1025][256]
#define OFF_WHT  (P1*L)                     // [1024][1025]  WHT_T[g][j] = (W_ih@H_r)[g][j]
#define OFF_W2T  (OFF_WHT + 1024*P1)        // [256][256]    W2T[c][i] = W2[i][c]
#define OFF_TE   (OFF_W2T + 256*256)        // u64 [2][1026] tagged e
#define OFF_TH   (OFF_TE + 2*1026*2)        // u64 [2][256]  tagged h

#define DYN_SMEM 143624

#define SCOPE_AGENT __HIP_MEMORY_SCOPE_AGENT

__device__ __forceinline__ u64 ld64(const u64* p) {
  return __hip_atomic_load(p, __ATOMIC_RELAXED, SCOPE_AGENT);
}
__device__ __forceinline__ void st64(u64* p, u64 v) {
  __hip_atomic_store(p, v, __ATOMIC_RELAXED, SCOPE_AGENT);
}
__device__ __forceinline__ u64 pk(float v, unsigned t) {
  return ((u64)t << 32) | (u64)__float_as_uint(v);
}
__device__ __forceinline__ unsigned tg_of(u64 x) { return (unsigned)(x >> 32); }
__device__ __forceinline__ float val_of(u64 x) { return __uint_as_float((unsigned)x); }

__device__ __forceinline__ float fast_tanh(float x) {
  float u = __expf(2.0f * x);
  return 1.0f - 2.0f * __builtin_amdgcn_rcpf(1.0f + u);
}
__device__ __forceinline__ float sigm(float x) {
  return __builtin_amdgcn_rcpf(1.0f + __expf(-x));
}
__device__ __forceinline__ float wave_reduce(float v) {
  #pragma unroll
  for (int o = 32; o > 0; o >>= 1) v += __shfl_xor(v, o, 64);
  return v;
}

__global__ void init_kernel(float* __restrict__ ws) {
  const int tid = threadIdx.x;
  u64* th = (u64*)(ws + OFF_TH);
  for (int i = tid; i < 256; i += 256) st64(th + i, 0ull);  // h(0): tag 0, val 0
}

// W2T[c][i] = W2[i][c], LDS-tiled transpose
__global__ void __launch_bounds__(256) w2t_kernel(const float* __restrict__ W2,
                                                  float* __restrict__ ws) {
  __shared__ float tile[64][65];
  const int bi = (blockIdx.x & 3) * 64;
  const int bc = (blockIdx.x >> 2) * 64;
  const int tx = threadIdx.x & 63, ty = threadIdx.x >> 6;
  for (int q = ty; q < 64; q += 4) tile[q][tx] = W2[(bi + q) * L + bc + tx];
  __syncthreads();
  float* W2T = ws + OFF_W2T;
  for (int q = ty; q < 64; q += 4) W2T[(bc + q) * L + bi + tx] = tile[tx][q];
}

// C[j][n] = sum_k H_r[j][k]*W[n][k]; W=[W1;W_ih]. VH row-major [j][i]; WHT transposed [g][j].
__global__ void __launch_bounds__(256) prep_gemm(const float* __restrict__ H,
                                                 const float* __restrict__ W1,
                                                 const float* __restrict__ W_ih,
                                                 float* __restrict__ ws) {
  __shared__ float As[32 * 64];
  __shared__ float Bs[64 * 33];
  const int tid = threadIdx.x;
  const int j0 = blockIdx.x * 64;
  const int n0 = blockIdx.y * 64;
  const int tx = tid & 15, ty = tid >> 4;
  float acc[4][4] = {{0.f,0.f,0.f,0.f},{0.f,0.f,0.f,0.f},{0.f,0.f,0.f,0.f},{0.f,0.f,0.f,0.f}};
  for (int ks = 0; ks < TWOL; ks += 32) {
    for (int idx = tid; idx < 2048; idx += 256) {
      int kk = idx >> 6, jj = idx & 63;
      int j = j0 + jj;
      As[kk * 64 + jj] = (j < P) ? H[(ks + kk) * P + j] : 0.0f;
    }
    for (int idx = tid; idx < 2048; idx += 256) {
      int kk = idx & 31, nn = idx >> 5;
      int n = n0 + nn;
      Bs[nn * 33 + kk] = (n < L) ? W1[n * TWOL + ks + kk] : W_ih[(n - L) * TWOL + ks + kk];
    }
    __syncthreads();
    #pragma unroll
    for (int kk = 0; kk < 32; ++kk) {
      float4 a = *(const float4*)&As[kk * 64 + ty * 4];
      #pragma unroll
      for (int r = 0; r < 4; ++r) {
        float bb = Bs[(tx * 4 + r) * 33 + kk];
        acc[r][0] += a.x * bb; acc[r][1] += a.y * bb;
        acc[r][2] += a.z * bb; acc[r][3] += a.w * bb;
      }
    }
    __syncthreads();
  }
  #pragma unroll
  for (int q = 0; q < 4; ++q) {
    int j = j0 + ty * 4 + q;
    if (j <= P) {
      int n = n0 + tx * 4;
      if (n < L) {
        float4 v = make_float4(acc[0][q], acc[1][q], acc[2][q], acc[3][q]);
        *(float4*)&ws[OFF_VH + j * L + n] = v;
      } else {
        #pragma unroll
        for (int r = 0; r < 4; ++r)
          ws[OFF_WHT + (n + r - L) * P1 + j] = acc[r][q];
      }
    }
  }
}

__global__ void __launch_bounds__(TPB, 1) scan_kernel(
    const float* __restrict__ W2, const float* __restrict__ b2,
    const float* __restrict__ w3, const float* __restrict__ cin,
    const float* __restrict__ W_hh, const float* __restrict__ b_ih,
    const float* __restrict__ b_hh,
    float* __restrict__ ws, float* __restrict__ out) {
  extern __shared__ float smem[];
  float* whts   = smem;             // 32768  WHT col-slice, swizzled [j][32]
  float* e_lds  = whts + 32768;     // 1026
  float* h_lds  = e_lds + 1026;     // 256
  float* x2p2   = h_lds + 256;      // [2][256]
  float* x2_lds = x2p2 + 512;       // 272 (padded i + (i>>4))
  float* hhp    = x2_lds + 272;     // [16][32]
  float* gxp    = hhp + 512;        // [16][32]
  float* gate_s = gxp + 512;        // 32
  float* sred   = gate_s + 32;      // 8
  float* cc_s   = sred + 8;         // 8

  const int tid = threadIdx.x;
  const int m = blockIdx.x;
  const int lane = tid & 63, wid = tid >> 6;
  u64* te = (u64*)(ws + OFF_TE);
  u64* th = (u64*)(ws + OFF_TH);

  const int row = tid >> 4, sub = tid & 15;   // f/e mapping: 32 rows x 16 threads
  const int io  = tid & 255, hf = tid >> 8;   // x2 GEMV mapping
  const int r   = tid & 31, ch = tid >> 5;    // hh / gx mapping
  const int j0  = 32 * m;                     // owned attention rows
  const int i0  = 8 * m;                      // owned h-indices
  const int G_r = (r >> 3) * L + i0 + (r & 7);

  // ---- preload registers ----
  const float* VH = ws + OFF_VH;
  float vh[16], vh2[16];
  #pragma unroll
  for (int q = 0; q < 16; ++q) vh[q] = VH[(j0 + row) * L + 16 * sub + q];
  #pragma unroll
  for (int q = 0; q < 16; ++q) vh2[q] = VH[1024 * L + 16 * sub + q];
  const bool xrow = (m == NBLK - 1) && (row == 0);   // this 16-thread group also does j=1024
  float w3r[16];
  #pragma unroll
  for (int q = 0; q < 16; ++q) w3r[q] = w3[16 * sub + q];
  float whh[16];
  #pragma unroll
  for (int q = 0; q < 16; ++q) whh[q] = W_hh[G_r * L + 16 * ch + q];
  const float b2r = (tid < 256) ? b2[tid] : 0.0f;
  const float hhb = (tid < 32) ? (b_ih[G_r] + b_hh[G_r]) : 0.0f;
  const float cb = cin[0];

  // ---- stage WHT column-slice into LDS (swizzled) ----
  for (int rr = 0; rr < 32; ++rr) {
    const int g = (rr >> 3) * L + i0 + (rr & 7);
    const float* src = ws + OFF_WHT + g * P1;
    for (int j = tid; j < 1024; j += TPB)
      whts[j * 32 + ((rr + j) & 31)] = src[j];
  }
  if (tid < 8) cc_s[tid] = 0.0f;
  __syncthreads();

  const float* w2t = ws + OFF_W2T;

  for (int t = 1; t <= P; ++t) {
    const int ppar = (t - 1) & 1, cpar = t & 1;
    const unsigned tprev = (unsigned)(t - 1), tcur = (unsigned)t;

    // phase1: poll h(t-1) — one tagged u64 per thread (tid<256)
    if (tid < 256) {
      const u64* hp = th + ppar * 256 + tid;
      u64 hv;
      for (;;) { hv = ld64(hp); if (__all(tg_of(hv) == tprev)) break; }
      h_lds[tid] = val_of(hv);
    }
    __syncthreads();                                   // B1

    // phase2: x2 half-GEMV (W2T from L2) + hh partial (W_hh in regs)
    {
      const int cbase = 128 * hf;
      float a0 = 0.f, a1 = 0.f, a2 = 0.f, a3 = 0.f;
      #pragma unroll 8
      for (int c = 0; c < 128; c += 4) {
        float4 hv4 = *(const float4*)&h_lds[cbase + c];
        a0 += w2t[(cbase + c) * L + io] * hv4.x;
        a1 += w2t[(cbase + c + 1) * L + io] * hv4.y;
        a2 += w2t[(cbase + c + 2) * L + io] * hv4.z;
        a3 += w2t[(cbase + c + 3) * L + io] * hv4.w;
      }
      x2p2[hf * 256 + io] = (a0 + a1) + (a2 + a3);
      float ah = 0.0f;
      #pragma unroll
      for (int q = 0; q < 16; ++q) ah += whh[q] * h_lds[16 * ch + q];
      hhp[ch * 32 + r] = ah;
    }
    __syncthreads();                                   // B2
    if (tid < 256) x2_lds[tid + (tid >> 4)] = b2r + x2p2[tid] + x2p2[256 + tid];
    __syncthreads();                                   // B3

    // phase4: f/e for own rows; hh reduce; e-poll
    float hhv = 0.0f;
    {
      float x2r[16];
      #pragma unroll
      for (int q = 0; q < 16; ++q) x2r[q] = x2_lds[17 * sub + q];
      float s = 0.0f;
      #pragma unroll
      for (int q = 0; q < 16; ++q) s += w3r[q] * fast_tanh(vh[q] + x2r[q]);
      #pragma unroll
      for (int o = 1; o < 16; o <<= 1) s += __shfl_xor(s, o, 64);
      if (sub == 0) {
        float vf = s + cb;
        out[t * P1 + j0 + row] = vf;
        st64(te + cpar * 1026 + j0 + row, pk(__expf(vf), tcur));
      }
      if (xrow) {                                      // terminal row j=1024
        float s2 = 0.0f;
        #pragma unroll
        for (int q = 0; q < 16; ++q) s2 += w3r[q] * fast_tanh(vh2[q] + x2r[q]);
        #pragma unroll
        for (int o = 1; o < 16; o <<= 1) s2 += __shfl_xor(s2, o, 64);
        if (sub == 0) {
          float vf2 = s2 + cb;
          out[t * P1 + 1024] = vf2;
          st64(te + cpar * 1026 + 1024, pk(__expf(vf2), tcur));
        }
      }
      if (tid < 32) {                                  // hh reduce (wave 0)
        #pragma unroll
        for (int q = 0; q < 16; ++q) hhv += hhp[q * 32 + tid];
        hhv += hhb;
      }
      // e-poll: 2 (or 3) tagged u64 per thread
      const u64* ep = te + cpar * 1026;
      const int ja = 2 * tid;
      const bool three = (tid == TPB - 1);
      u64 e0, e1, e2 = 0;
      for (;;) {
        e0 = ld64(ep + ja); e1 = ld64(ep + ja + 1);
        bool ok = (tg_of(e0) == tcur) & (tg_of(e1) == tcur);
        if (three) { e2 = ld64(ep + 1024); ok &= (tg_of(e2) == tcur); }
        if (__all(ok)) break;
      }
      e_lds[ja] = val_of(e0); e_lds[ja + 1] = val_of(e1);
      float se = val_of(e0) + val_of(e1);
      if (three) { e_lds[1024] = val_of(e2); se += val_of(e2); }
      se = wave_reduce(se);
      if (lane == 0) sred[wid] = se;
    }
    __syncthreads();                                   // B4

    // phase5: gx partial for own 32 gate rows over j-chunk
    {
      const int jb = 64 * ch;
      float acc = 0.0f;
      #pragma unroll 4
      for (int q = 0; q < 64; q += 4) {
        const int j = jb + q;
        float4 ev4 = *(const float4*)&e_lds[j];
        acc += ev4.x * whts[j * 32 + ((r + j) & 31)];
        acc += ev4.y * whts[(j + 1) * 32 + ((r + j + 1) & 31)];
        acc += ev4.z * whts[(j + 2) * 32 + ((r + j + 2) & 31)];
        acc += ev4.w * whts[(j + 3) * 32 + ((r + j + 3) & 31)];
      }
      gxp[ch * 32 + r] = acc;
    }
    __syncthreads();                                   // B5

    // phase6: gates + cell + publish h (wave 0 only; in-wave LDS ordering)
    if (tid < 32) {
      float S = sred[0] + sred[1] + sred[2] + sred[3]
              + sred[4] + sred[5] + sred[6] + sred[7];
      float gx = 0.0f;
      #pragma unroll
      for (int q = 0; q < 16; ++q) gx += gxp[q * 32 + tid];
      gate_s[tid] = gx * __builtin_amdgcn_rcpf(S) + hhv;
    }
    if (tid < 8) {
      float gi = gate_s[tid], gf = gate_s[8 + tid];
      float gg = gate_s[16 + tid], go = gate_s[24 + tid];
      float cn = sigm(gf) * cc_s[tid] + sigm(gi) * fast_tanh(gg);
      float hn = sigm(go) * fast_tanh(cn);
      cc_s[tid] = cn;
      st64(th + cpar * 256 + i0 + tid, pk(hn, tcur));
    }
    // no trailing barrier needed: next-step LDS uses are barrier-separated
  }
}

__global__ void __launch_bounds__(256) final_kernel(float* __restrict__ out) {
  __shared__ float buf[P1];
  __shared__ float red[8];
  const int row = blockIdx.x;
  const int tid = threadIdx.x;
  const int lane = tid & 63, wid = tid >> 6;
  if (row == 0) {
    const float v = -logf((float)P1);
    for (int idx = tid; idx < P1; idx += 256) out[idx] = v;
    return;
  }
  float* o = out + row * P1;
  for (int idx = tid; idx < P1; idx += 256) buf[idx] = o[idx];
  __syncthreads();
  float p = 0.0f;
  for (int idx = tid; idx < P1; idx += 256) p += __expf(buf[idx]);
  p = wave_reduce(p);
  if (lane == 0) red[wid] = p;
  __syncthreads();
  const float s1 = red[0] + red[1] + red[2] + red[3];
  const float inv = __builtin_amdgcn_rcpf(s1);
  __syncthreads();
  float p2 = 0.0f;
  for (int idx = tid; idx < P1; idx += 256) {
    float be = __expf(buf[idx]) * inv;   // beta
    buf[idx] = be;
    p2 += __expf(be);
  }
  p2 = wave_reduce(p2);
  if (lane == 0) red[wid] = p2;
  __syncthreads();
  const float ls2 = logf(red[0] + red[1] + red[2] + red[3]);
  for (int idx = tid; idx < P1; idx += 256) o[idx] = buf[idx] - ls2;
}

extern "C" void kernel_launch(void* const* d_in, const int* in_sizes, int n_in,
                              void* d_out, int out_size, void* d_ws, size_t ws_size,
                              hipStream_t stream) {
  (void)in_sizes; (void)n_in; (void)out_size; (void)ws_size;
  const float* H    = (const float*)d_in[0];
  const float* W1   = (const float*)d_in[1];
  const float* W2   = (const float*)d_in[2];
  const float* b2   = (const float*)d_in[3];
  const float* w3   = (const float*)d_in[4];
  const float* c    = (const float*)d_in[5];
  const float* W_ih = (const float*)d_in[6];
  const float* W_hh = (const float*)d_in[7];
  const float* b_ih = (const float*)d_in[8];
  const float* b_hh = (const float*)d_in[9];
  float* out = (float*)d_out;
  float* ws  = (float*)d_ws;

  hipFuncSetAttribute(reinterpret_cast<const void*>(scan_kernel),
                      hipFuncAttributeMaxDynamicSharedMemorySize, 160 * 1024);

  hipLaunchKernelGGL(init_kernel, dim3(1), dim3(256), 0, stream, ws);
  hipLaunchKernelGGL(w2t_kernel, dim3(16), dim3(256), 0, stream, W2, ws);
  hipLaunchKernelGGL(prep_gemm, dim3(17, 20), dim3(256), 0, stream, H, W1, W_ih, ws);
  hipLaunchKernelGGL(scan_kernel, dim3(NBLK), dim3(TPB), DYN_SMEM, stream,
                     W2, b2, w3, c, W_hh, b_ih, b_hh, ws, out);
  hipLaunchKernelGGL(final_kernel, dim3(P1), dim3(256), 0, stream, out);
}

// Round 6
// 5918.585 us; speedup vs baseline: 2.2020x; 2.2020x over previous
//
#include <hip/hip_runtime.h>
#include <math.h>

#define L 256
#define P 1024
#define P1 1025
#define TWOL 512
#define NATT 32
#define NCELL 8
#define NBLK (NATT + NCELL)
#define TPB 512

typedef unsigned long long u64;

// ws offsets (float units)
#define OFF_VH    0                              // [1025][256]
#define OFF_WHJG  (P1*L)                         // [1024][1024]  WH[j][g]
#define OFF_GX    (OFF_WHJG + 1024*1024)         // [2][32][1024] gx partials
#define OFF_X2P   (OFF_GX + 2*32*1024)           // [2][8][256]   x2 partials
#define OFF_HB    (OFF_X2P + 2*8*256)            // [2][256]      h
#define OFF_TAGA  (OFF_HB + 2*256)               // u64[32*16] att tags (128B strided)
#define OFF_TAGC  (OFF_TAGA + 32*16*2)           // u64[8*16] cell tags

#define DYN_SMEM 139264

#define SCOPE_AGENT __HIP_MEMORY_SCOPE_AGENT

__device__ __forceinline__ float ldc(const float* p) {
  return __hip_atomic_load(p, __ATOMIC_RELAXED, SCOPE_AGENT);
}
__device__ __forceinline__ void stc(float* p, float v) {
  __hip_atomic_store(p, v, __ATOMIC_RELAXED, SCOPE_AGENT);
}
__device__ __forceinline__ u64 ld64(const u64* p) {
  return __hip_atomic_load(p, __ATOMIC_RELAXED, SCOPE_AGENT);
}
__device__ __forceinline__ void st64(u64* p, u64 v) {
  __hip_atomic_store(p, v, __ATOMIC_RELAXED, SCOPE_AGENT);
}
__device__ __forceinline__ u64 pk(float v, unsigned t) {
  return ((u64)t << 32) | (u64)__float_as_uint(v);
}
__device__ __forceinline__ unsigned tg_of(u64 x) { return (unsigned)(x >> 32); }
__device__ __forceinline__ float val_of(u64 x) { return __uint_as_float((unsigned)x); }

__device__ __forceinline__ float fast_tanh(float x) {
  float u = __expf(2.0f * x);
  return 1.0f - 2.0f * __builtin_amdgcn_rcpf(1.0f + u);
}
__device__ __forceinline__ float sigm(float x) {
  return __builtin_amdgcn_rcpf(1.0f + __expf(-x));
}
__device__ __forceinline__ float wave_reduce(float v) {
  #pragma unroll
  for (int o = 32; o > 0; o >>= 1) v += __shfl_xor(v, o, 64);
  return v;
}

__global__ void init_kernel(float* __restrict__ ws) {
  const int tid = threadIdx.x;
  u64* tg = (u64*)(ws + OFF_TAGA);
  for (int i = tid; i < (NATT + NCELL) * 16; i += 256) st64(tg + i, 0ull);
}

// VH[j][i] (i<256) and WH[j][g] (g = n-256); H_r row 1024 = 0.
__global__ void __launch_bounds__(256) prep_gemm(const float* __restrict__ H,
                                                 const float* __restrict__ W1,
                                                 const float* __restrict__ W_ih,
                                                 float* __restrict__ ws) {
  __shared__ float As[32 * 64];
  __shared__ float Bs[64 * 33];
  const int tid = threadIdx.x;
  const int j0 = blockIdx.x * 64;
  const int n0 = blockIdx.y * 64;
  const int tx = tid & 15, ty = tid >> 4;
  float acc[4][4] = {{0.f,0.f,0.f,0.f},{0.f,0.f,0.f,0.f},{0.f,0.f,0.f,0.f},{0.f,0.f,0.f,0.f}};
  for (int ks = 0; ks < TWOL; ks += 32) {
    for (int idx = tid; idx < 2048; idx += 256) {
      int kk = idx >> 6, jj = idx & 63;
      int j = j0 + jj;
      As[kk * 64 + jj] = (j < P) ? H[(ks + kk) * P + j] : 0.0f;
    }
    for (int idx = tid; idx < 2048; idx += 256) {
      int kk = idx & 31, nn = idx >> 5;
      int n = n0 + nn;
      Bs[nn * 33 + kk] = (n < L) ? W1[n * TWOL + ks + kk] : W_ih[(n - L) * TWOL + ks + kk];
    }
    __syncthreads();
    #pragma unroll
    for (int kk = 0; kk < 32; ++kk) {
      float4 a = *(const float4*)&As[kk * 64 + ty * 4];
      #pragma unroll
      for (int r = 0; r < 4; ++r) {
        float bb = Bs[(tx * 4 + r) * 33 + kk];
        acc[r][0] += a.x * bb; acc[r][1] += a.y * bb;
        acc[r][2] += a.z * bb; acc[r][3] += a.w * bb;
      }
    }
    __syncthreads();
  }
  #pragma unroll
  for (int q = 0; q < 4; ++q) {
    int j = j0 + ty * 4 + q;
    int n = n0 + tx * 4;
    if (n < L) {
      if (j <= P) {
        float4 v = make_float4(acc[0][q], acc[1][q], acc[2][q], acc[3][q]);
        *(float4*)&ws[OFF_VH + j * L + n] = v;
      }
    } else {
      if (j < P) {
        #pragma unroll
        for (int r = 0; r < 4; ++r)
          ws[OFF_WHJG + j * 1024 + (n + r - L)] = acc[r][q];
      }
    }
  }
}

__global__ void __launch_bounds__(TPB, 1) scan_kernel(
    const float* __restrict__ W2, const float* __restrict__ b2,
    const float* __restrict__ w3, const float* __restrict__ cin,
    const float* __restrict__ W_hh, const float* __restrict__ b_ih,
    const float* __restrict__ b_hh,
    float* __restrict__ ws, float* __restrict__ out) {
  extern __shared__ float smem[];
  const int tid = threadIdx.x;
  const int blk = blockIdx.x;
  const int lane = tid & 63, wid = tid >> 6;
  float* gxf = ws + OFF_GX;
  u64*  gxu  = (u64*)gxf;
  float* x2p = ws + OFF_X2P;
  float* hb  = ws + OFF_HB;
  u64* taga = (u64*)(ws + OFF_TAGA);
  u64* tagc = (u64*)(ws + OFF_TAGC);

  if (blk < NATT) {
    // ================= attention role =================
    const int b = blk;
    const int j0 = 32 * b;
    float* wt   = smem;            // [32][1024]
    float* x2s  = smem + 32768;    // 272 padded
    float* es   = x2s + 272;       // 36
    float* sred = es + 36;         // 1
    const int row = tid >> 4, sub = tid & 15;

    for (int idx = tid; idx < 32768; idx += TPB)
      wt[idx] = ws[OFF_WHJG + (j0 + (idx >> 10)) * 1024 + (idx & 1023)];
    float vh[16];
    #pragma unroll
    for (int qq = 0; qq < 16; ++qq) vh[qq] = ws[OFF_VH + (j0 + row) * L + 16 * sub + qq];
    float w3r[16];
    #pragma unroll
    for (int qq = 0; qq < 16; ++qq) w3r[qq] = w3[16 * sub + qq];
    const bool xr = (b == NATT - 1) && (row == 0);   // handles terminal j=1024 (VH row = 0)
    const float b2r = (tid < 256) ? b2[tid] : 0.0f;
    const float cb = cin[0];
    __syncthreads();

    for (int t = 1; t <= P; ++t) {
      const int par = t & 1;
      // wait x2p(t) from all cell blocks
      if (wid == 0) {
        u64 tv;
        for (;;) {
          tv = (lane < NCELL) ? ld64(tagc + lane * 16) : ~0ull;
          if (__all(tg_of(tv) >= (unsigned)t)) break;
        }
      }
      __syncthreads();                                 // B1
      if (tid < 256) {
        const float* xp = x2p + par * NCELL * L;
        float a[NCELL];
        #pragma unroll
        for (int qq = 0; qq < NCELL; ++qq) a[qq] = ldc(xp + qq * L + tid);
        float v = b2r;
        #pragma unroll
        for (int qq = 0; qq < NCELL; ++qq) v += a[qq];
        x2s[tid + (tid >> 4)] = v;
      }
      __syncthreads();                                 // B2
      {
        float x2r[16];
        #pragma unroll
        for (int qq = 0; qq < 16; ++qq) x2r[qq] = x2s[17 * sub + qq];
        float s = 0.0f;
        #pragma unroll
        for (int qq = 0; qq < 16; ++qq) s += w3r[qq] * fast_tanh(vh[qq] + x2r[qq]);
        #pragma unroll
        for (int o = 1; o < 16; o <<= 1) s += __shfl_xor(s, o, 64);
        if (sub == 0) {
          float vf = s + cb;
          out[t * P1 + j0 + row] = vf;
          es[row] = __expf(vf);
        }
        if (xr) {
          float s2 = 0.0f;
          #pragma unroll
          for (int qq = 0; qq < 16; ++qq) s2 += w3r[qq] * fast_tanh(x2r[qq]);
          #pragma unroll
          for (int o = 1; o < 16; o <<= 1) s2 += __shfl_xor(s2, o, 64);
          if (sub == 0) {
            float vf2 = s2 + cb;
            out[t * P1 + 1024] = vf2;
            es[32] = __expf(vf2);
          }
        }
      }
      __syncthreads();                                 // B3
      {
        // gx partial: own 32 e's x WHT slice; thread owns g = {2*tid, 2*tid+1}
        float ax = 0.0f, ay = 0.0f;
        #pragma unroll 8
        for (int jj = 0; jj < 32; ++jj) {
          float e = es[jj];
          float2 wv = *(const float2*)&wt[jj * 1024 + 2 * tid];
          ax += e * wv.x; ay += e * wv.y;
        }
        u64 pkd = ((u64)__float_as_uint(ay) << 32) | (u64)__float_as_uint(ax);
        st64(gxu + (size_t)par * NATT * 512 + b * 512 + tid, pkd);
        if (wid == 0) {
          const int nE = (b == NATT - 1) ? 33 : 32;
          float ev = (lane < nE) ? es[lane] : 0.0f;
          ev = wave_reduce(ev);
          if (lane == 0) sred[0] = ev;
        }
      }
      __syncthreads();                                 // B4: drains gx st64s (vmcnt0 before barrier)
      if (tid == 0) st64(taga + b * 16, pk(sred[0], (unsigned)t));
    }
  } else {
    // ================= cell role =================
    const int q = blk - NATT;
    const int i0 = 32 * q;
    float* whh = smem;             // [256][128] swizzled: whh[k*128 + ((r+k)&127)]
    float* hs  = whh + 32768;      // 256
    float* hhp = hs + 256;         // [4][128]
    float* prt = hhp + 512;        // [4][128]
    float* gts = prt + 512;        // 128
    float* hwn = gts + 128;        // 32
    float* scs = hwn + 32;         // 1
    const int rl = tid & 127, qr = tid >> 7;
    const int G = (rl >> 5) * L + i0 + (rl & 31);     // global gate row for rl

    // prologue publish: x2p(1) = W2@h0 = 0, h(0) = 0
    if (tid < 256) stc(x2p + 1 * NCELL * L + q * L + tid, 0.0f);
    if (tid < 32)  stc(hb + 0 * L + i0 + tid, 0.0f);
    __syncthreads();
    if (tid == 0) st64(tagc + q * 16, ((u64)1) << 32);

    // staging (off critical path)
    for (int idx = tid; idx < 32768; idx += TPB) {
      int rr = idx >> 8, k = idx & 255;
      int g2 = (rr >> 5) * L + i0 + (rr & 31);
      whh[k * 128 + ((rr + k) & 127)] = W_hh[g2 * L + k];
    }
    float w2r[32];
    if (tid < 256) {
      #pragma unroll
      for (int ii = 0; ii < 32; ++ii) w2r[ii] = W2[tid * L + i0 + ii];
    }
    const float bz = (tid < 128) ? (b_ih[G] + b_hh[G]) : 0.0f;
    float creg = 0.0f;                                 // c-state (wave0 lanes<32)
    __syncthreads();

    for (int t = 1; t <= P; ++t) {
      const int par = t & 1, hpar = (t - 1) & 1;
      // peers' h(t-1) ready?
      if (wid == 0) {
        u64 tv;
        for (;;) {
          tv = (lane < NCELL) ? ld64(tagc + lane * 16) : ~0ull;
          if (__all(tg_of(tv) >= (unsigned)t)) break;
        }
      }
      __syncthreads();                                 // B1
      if (tid < 256) hs[tid] = ldc(hb + hpar * L + tid);
      __syncthreads();                                 // B2
      {  // hh partial (overlaps attention phase)
        float a = 0.0f;
        #pragma unroll 16
        for (int m = 0; m < 64; ++m) {
          int k = 64 * qr + m;
          a += whh[k * 128 + ((rl + k) & 127)] * hs[k];
        }
        hhp[qr * 128 + rl] = a;
      }
      if (wid == 0) {  // att tags: detect + gather S partials
        u64 tv;
        for (;;) {
          tv = (lane < NATT) ? ld64(taga + lane * 16) : ~0ull;
          if (__all(tg_of(tv) >= (unsigned)t)) break;
        }
        float sv = (lane < NATT) ? val_of(tv) : 0.0f;
        sv = wave_reduce(sv);
        if (lane == 0) scs[0] = sv;
      }
      __syncthreads();                                 // B3
      {  // batch-read gx partials for own 128 gate rows (8 blocks per quarter)
        const float* gp = gxf + (size_t)par * NATT * 1024;
        float a[8];
        #pragma unroll
        for (int bb = 0; bb < 8; ++bb)
          a[bb] = ldc(gp + (size_t)(8 * qr + bb) * 1024 + G);
        float s = 0.0f;
        #pragma unroll
        for (int bb = 0; bb < 8; ++bb) s += a[bb];
        prt[qr * 128 + rl] = s;
      }
      __syncthreads();                                 // B4
      if (tid < 128) {
        float gx = prt[tid] + prt[128 + tid] + prt[256 + tid] + prt[384 + tid];
        float hh = hhp[tid] + hhp[128 + tid] + hhp[256 + tid] + hhp[384 + tid];
        gts[tid] = gx * __builtin_amdgcn_rcpf(scs[0]) + hh + bz;
      }
      __syncthreads();                                 // B5
      if (wid == 0 && lane < 32) {
        float gi = gts[lane], gf = gts[32 + lane];
        float gg = gts[64 + lane], go = gts[96 + lane];
        float cn = sigm(gf) * creg + sigm(gi) * fast_tanh(gg);
        float hn = sigm(go) * fast_tanh(cn);
        creg = cn;
        hwn[lane] = hn;
        stc(hb + par * L + i0 + lane, hn);
      }
      __syncthreads();                                 // B6
      if (tid < 256) {  // x2 partial for step t+1 (W2 slice in regs)
        float xv = 0.0f;
        #pragma unroll
        for (int ii = 0; ii < 32; ++ii) xv += w2r[ii] * hwn[ii];
        stc(x2p + ((t + 1) & 1) * NCELL * L + q * L + tid, xv);
      }
      __syncthreads();                                 // B7: drain before tag
      if (tid == 0) st64(tagc + q * 16, ((u64)(t + 1)) << 32);
    }
  }
}

__global__ void __launch_bounds__(256) final_kernel(float* __restrict__ out) {
  __shared__ float buf[P1];
  __shared__ float red[8];
  const int row = blockIdx.x;
  const int tid = threadIdx.x;
  const int lane = tid & 63, wid = tid >> 6;
  if (row == 0) {
    const float v = -logf((float)P1);
    for (int idx = tid; idx < P1; idx += 256) out[idx] = v;
    return;
  }
  float* o = out + row * P1;
  for (int idx = tid; idx < P1; idx += 256) buf[idx] = o[idx];
  __syncthreads();
  float p = 0.0f;
  for (int idx = tid; idx < P1; idx += 256) p += __expf(buf[idx]);
  p = wave_reduce(p);
  if (lane == 0) red[wid] = p;
  __syncthreads();
  const float s1 = red[0] + red[1] + red[2] + red[3];
  const float inv = __builtin_amdgcn_rcpf(s1);
  __syncthreads();
  float p2 = 0.0f;
  for (int idx = tid; idx < P1; idx += 256) {
    float be = __expf(buf[idx]) * inv;   // beta
    buf[idx] = be;
    p2 += __expf(be);
  }
  p2 = wave_reduce(p2);
  if (lane == 0) red[wid] = p2;
  __syncthreads();
  const float ls2 = logf(red[0] + red[1] + red[2] + red[3]);
  for (int idx = tid; idx < P1; idx += 256) o[idx] = buf[idx] - ls2;
}

extern "C" void kernel_launch(void* const* d_in, const int* in_sizes, int n_in,
                              void* d_out, int out_size, void* d_ws, size_t ws_size,
                              hipStream_t stream) {
  (void)in_sizes; (void)n_in; (void)out_size; (void)ws_size;
  const float* H    = (const float*)d_in[0];
  const float* W1   = (const float*)d_in[1];
  const float* W2   = (const float*)d_in[2];
  const float* b2   = (const float*)d_in[3];
  const float* w3   = (const float*)d_in[4];
  const float* c    = (const float*)d_in[5];
  const float* W_ih = (const float*)d_in[6];
  const float* W_hh = (const float*)d_in[7];
  const float* b_ih = (const float*)d_in[8];
  const float* b_hh = (const float*)d_in[9];
  float* out = (float*)d_out;
  float* ws  = (float*)d_ws;

  hipFuncSetAttribute(reinterpret_cast<const void*>(scan_kernel),
                      hipFuncAttributeMaxDynamicSharedMemorySize, 160 * 1024);

  hipLaunchKernelGGL(init_kernel, dim3(1), dim3(256), 0, stream, ws);
  hipLaunchKernelGGL(prep_gemm, dim3(17, 20), dim3(256), 0, stream, H, W1, W_ih, ws);
  hipLaunchKernelGGL(scan_kernel, dim3(NBLK), dim3(TPB), DYN_SMEM, stream,
                     W2, b2, w3, c, W_hh, b_ih, b_hh, ws, out);
  hipLaunchKernelGGL(final_kernel, dim3(P1), dim3(256), 0, stream, out);
}